// Round 9
// baseline (906.101 us; speedup 1.0000x reference)
//
#include <hip/hip_runtime.h>
#include <hip/hip_bf16.h>
#include <cstdint>

typedef __attribute__((ext_vector_type(4))) float f32x4;
typedef __attribute__((ext_vector_type(8))) short bf16x8;
typedef __attribute__((ext_vector_type(4))) short bf16x4;
typedef __attribute__((ext_vector_type(4))) unsigned int u32x4;

#define DEV static __device__ __forceinline__

// round-to-nearest-even f32 -> bf16 (bit pattern)
DEV unsigned short f2bf(float f) {
    union { float f; unsigned int u; } v; v.f = f;
    unsigned int u = v.u;
    return (unsigned short)((u + 0x7FFFu + ((u >> 16) & 1u)) >> 16);
}

// pack 2 f32 -> 2 bf16 (RNE) in one u32 (low = a)
DEV unsigned int pkbf(float a, float b) {
    return ((unsigned int)f2bf(b) << 16) | f2bf(a);
}

// async global->LDS 16B per lane; LDS dest = wave-uniform base + lane*16
DEV void async_cp16(const void* g, void* l) {
    __builtin_amdgcn_global_load_lds(
        (const __attribute__((address_space(1))) unsigned int*)g,
        (__attribute__((address_space(3))) unsigned int*)l,
        16, 0, 0);
}

// stage one 128x64 bf16 half-tile (16KB): 512 threads x 2 chunks of 16B.
// linear LDS dest, inverse-swizzled global source (involution: slot^=(row&7)).
DEV void stage_half(const unsigned short* __restrict__ g, long kofs,
                    unsigned short* l, int tid, int gpitch) {
#pragma unroll
    for (int i = 0; i < 2; ++i) {
        int c = i * 512 + tid;
        int row = c >> 3;
        int ss = (c & 7) ^ (row & 7);
        async_cp16(g + (long)row * gpitch + kofs + ss * 8,
                   l + (i * 512 + (tid & 448)) * 8);
    }
}

// swizzled LDS fragment read (bank-conflict-free pair of the stage swizzle)
DEV bf16x8 ldsrd(const unsigned short* base, int r, int q) {
    return *(const bf16x8*)&base[r * 64 + ((q ^ (r & 7)) << 3)];
}

#define BAR __builtin_amdgcn_s_barrier();
#define SCB __builtin_amdgcn_sched_barrier(0);
#define LGKM0 asm volatile("s_waitcnt lgkmcnt(0)");
#define P1 __builtin_amdgcn_s_setprio(1);
#define P0 __builtin_amdgcn_s_setprio(0);
#define VM0 asm volatile("s_waitcnt vmcnt(0)" ::: "memory");
#define VM2 asm volatile("s_waitcnt vmcnt(2)" ::: "memory");
#define VM8 asm volatile("s_waitcnt vmcnt(8)" ::: "memory");

#define MG(AF, BF, RI0, CJ0)                                                  \
    _Pragma("unroll") for (int kq = 0; kq < 2; ++kq)                          \
    _Pragma("unroll") for (int i = 0; i < 4; ++i)                             \
    _Pragma("unroll") for (int j = 0; j < 2; ++j)                             \
        acc[RI0 + i][CJ0 + j] = __builtin_amdgcn_mfma_f32_16x16x32_bf16(      \
            AF[kq][i], BF[kq][j], acc[RI0 + i][CJ0 + j], 0, 0, 0);

#define RD_AF0(L) _Pragma("unroll") for (int kq = 0; kq < 2; ++kq)            \
    _Pragma("unroll") for (int i = 0; i < 4; ++i)                             \
        af0[kq][i] = ldsrd(L, i * 16 + llo, kq * 4 + lhi);
#define RD_AF1(L) _Pragma("unroll") for (int kq = 0; kq < 2; ++kq)            \
    _Pragma("unroll") for (int i = 0; i < 4; ++i)                             \
        af1[kq][i] = ldsrd(L, 64 + i * 16 + llo, kq * 4 + lhi);
#define RD_BF0(L) _Pragma("unroll") for (int kq = 0; kq < 2; ++kq)            \
    _Pragma("unroll") for (int j = 0; j < 2; ++j)                             \
        bf0[kq][j] = ldsrd(L, br0 + j * 16 + llo, kq * 4 + lhi);
#define RD_BF1(L) _Pragma("unroll") for (int kq = 0; kq < 2; ++kq)            \
    _Pragma("unroll") for (int j = 0; j < 2; ++j)                             \
        bf1[kq][j] = ldsrd(L, br0 + 32 + j * 16 + llo, kq * 4 + lhi);

// ---------------------------------------------------------------------------
// 256x256 8-wave GEMM core (R8 structure, proven): used by down_gemm.
// ---------------------------------------------------------------------------
template <int NT>
DEV void gemm256(const unsigned short* __restrict__ gA,
                 const unsigned short* __restrict__ gB,
                 const int gpitch, unsigned short* lds,
                 f32x4 (&acc)[8][4], const int tid) {
    const int lane = tid & 63;
    const int wv = tid >> 6;
    const int wr = wv >> 2;
    const int wcq = wv & 3;
    const int lhi = lane >> 4, llo = lane & 15;
    const int hb = wcq >> 1;
    const int br0 = (wcq & 1) * 64;

    const unsigned short* lA0 = lds + (0 * 2 + wr) * 8192;
    const unsigned short* lA1 = lds + (1 * 2 + wr) * 8192;
    const unsigned short* lB0 = lds + 32768 + (0 * 2 + hb) * 8192;
    const unsigned short* lB1 = lds + 32768 + (1 * 2 + hb) * 8192;

#define SA0(BUF, K) stage_half(gA, K, lds + ((BUF) * 2 + 0) * 8192, tid, gpitch);
#define SA1(BUF, K) stage_half(gA + (long)128 * gpitch, K, lds + ((BUF) * 2 + 1) * 8192, tid, gpitch);
#define SB0(BUF, K) stage_half(gB, K, lds + 32768 + ((BUF) * 2 + 0) * 8192, tid, gpitch);
#define SB1(BUF, K) stage_half(gB + (long)128 * gpitch, K, lds + 32768 + ((BUF) * 2 + 1) * 8192, tid, gpitch);

    SA0(0, 0) SA1(0, 0) SB0(0, 0) SB1(0, 0)
    SA0(1, 64)
    VM2
    BAR

    bf16x8 af0[2][4], af1[2][4], bf0[2][2], bf1[2][2];

    for (int it = 0; it < NT / 2; ++it) {
        const long kO  = (long)(2 * it + 1) * 64;
        const long kE2 = (long)(2 * it + 2) * 64;
        const long kO2 = (long)(2 * it + 3) * 64;
        const bool pf = (it + 1 < NT / 2);

        // tile E (buf0)
        RD_AF0(lA0) RD_BF0(lB0)
        SA1(1, kO)
        BAR LGKM0 SCB
        P1 MG(af0, bf0, 0, 0) P0
        BAR
        RD_BF1(lB0)
        SB0(1, kO)
        BAR LGKM0 SCB
        P1 MG(af0, bf1, 0, 2) P0
        BAR
        RD_AF1(lA0)
        SB1(1, kO)
        BAR LGKM0 SCB
        P1 MG(af1, bf0, 4, 0) P0
        BAR
        if (pf) { SA0(0, kE2) }
        BAR
        P1 MG(af1, bf1, 4, 2) P0
        if (pf) { VM2 } else { VM0 }
        BAR SCB

        // tile O (buf1)
        RD_AF0(lA1) RD_BF0(lB1)
        if (pf) { SA1(0, kE2) }
        BAR LGKM0 SCB
        P1 MG(af0, bf0, 0, 0) P0
        BAR
        RD_BF1(lB1)
        if (pf) { SB0(0, kE2) }
        BAR LGKM0 SCB
        P1 MG(af0, bf1, 0, 2) P0
        BAR
        RD_AF1(lA1)
        if (pf) { SB1(0, kE2) }
        BAR LGKM0 SCB
        P1 MG(af1, bf0, 4, 0) P0
        BAR
        if (pf) { SA0(1, kO2) }
        BAR
        P1 MG(af1, bf1, 4, 2) P0
        if (pf) { VM2 }
        BAR SCB
    }
#undef SA0
#undef SA1
#undef SB0
#undef SB1
}

// ---------------------------------------------------------------------------
// Kernel 0: weight prep.
//  w12t[n][k]: n even -> bf16(w0[k]*w1[k][n/2]), n odd -> bf16(w0[k]*w2[k][n/2])
//  w3t[j][n] = bf16(w3[n][j])   (1024 x 512, n contiguous)
// ---------------------------------------------------------------------------
__global__ void prep_w(const float* __restrict__ w0, const float* __restrict__ w1,
                       const float* __restrict__ w2, const float* __restrict__ w3,
                       unsigned short* __restrict__ w12t, unsigned short* __restrict__ w3t) {
    int t = blockIdx.x * 256 + threadIdx.x;
    if (t < 1048576) {
        int n = t >> 10, k = t & 1023;
        const float* src = (n & 1) ? w2 : w1;
        w12t[t] = f2bf(w0[k] * src[k * 512 + (n >> 1)]);
    } else {
        int idx = t - 1048576;
        int j = idx >> 9, n = idx & 511;
        w3t[idx] = f2bf(w3[n * 1024 + j]);
    }
}

// ---------------------------------------------------------------------------
// Kernel 1: x3 = silu_gate(rmsnorm-fused xb @ w12t^T). 256x256 tile, K=1024.
// A is reg-staged from f32 x: ph2 issues 8x dwordx4 (A[t+1]); ph3 cvt+sumsq
// +swizzled ds_write. l = rsqrt(mean(x^2)) applied in epilogue (linear).
// Per thread: rows (tid>>2) and 128+(tid>>2) of the block tile; 4x16B f32
// chunks per row per K-tile at col segment (tid&3)*16.
// ---------------------------------------------------------------------------
__global__ __launch_bounds__(512, 2)
void gate_gemm(const float* __restrict__ x,
               const unsigned short* __restrict__ w12t,
               unsigned short* __restrict__ x3) {
    __shared__ unsigned short lds[65536];    // 128 KB
    __shared__ float spart[1024];            // [256 rows][4 partials]
    __shared__ float lrow[256];

    const int tid = threadIdx.x;
    const int lane = tid & 63;
    const int wv = tid >> 6;
    const int wr = wv >> 2, wcq = wv & 3;
    const int lhi = lane >> 4, llo = lane & 15;
    const int hb = wcq >> 1;
    const int br0 = (wcq & 1) * 64;

    int bid = blockIdx.x;                    // 2048 blocks
    int wgid = (bid & 7) * 256 + (bid >> 3); // bijective XCD chunks
    const int mt = wgid >> 2, nt = wgid & 3;

    const unsigned short* gB = w12t + (long)nt * 256 * 1024;
    const int arow = tid >> 2;               // row within 128-half
    const int acol = tid & 3;                // 64B f32 segment
    const float* gxr0 = x + (long)(mt * 256 + arow) * 1024 + acol * 16;
    const float* gxr1 = gxr0 + (long)128 * 1024;
    const int ws0 = (((acol * 2)     ^ (arow & 7)) << 3);  // ushort offs
    const int ws1 = (((acol * 2 + 1) ^ (arow & 7)) << 3);

    f32x4 ar[2][4];
    float sq0 = 0.f, sq1 = 0.f;

#define ALOAD(KOFS) { _Pragma("unroll") for (int c = 0; c < 4; ++c) {          \
        ar[0][c] = *(const f32x4*)(gxr0 + (KOFS) + c * 4);                     \
        ar[1][c] = *(const f32x4*)(gxr1 + (KOFS) + c * 4); } }

#define ACVT(D) { _Pragma("unroll") for (int h2 = 0; h2 < 2; ++h2) {           \
        float s = 0.f; unsigned int pk[8];                                     \
        _Pragma("unroll") for (int c = 0; c < 4; ++c) {                        \
            f32x4 v = ar[h2][c];                                               \
            s += v.x * v.x + v.y * v.y + v.z * v.z + v.w * v.w;                \
            pk[c * 2]     = pkbf(v.x, v.y);                                    \
            pk[c * 2 + 1] = pkbf(v.z, v.w); }                                  \
        if (h2 == 0) sq0 += s; else sq1 += s;                                  \
        unsigned short* dst = lds + ((D) * 2 + h2) * 8192 + arow * 64;         \
        *(u32x4*)(dst + ws0) = (u32x4){pk[0], pk[1], pk[2], pk[3]};            \
        *(u32x4*)(dst + ws1) = (u32x4){pk[4], pk[5], pk[6], pk[7]}; } }

#define SB0G(BUF, K) stage_half(gB, K, lds + 32768 + ((BUF) * 2 + 0) * 8192, tid, 1024);
#define SB1G(BUF, K) stage_half(gB + (long)128 * 1024, K, lds + 32768 + ((BUF) * 2 + 1) * 8192, tid, 1024);

    f32x4 acc[8][4];
#pragma unroll
    for (int i = 0; i < 8; ++i)
#pragma unroll
        for (int j = 0; j < 4; ++j) acc[i][j] = (f32x4){0.f, 0.f, 0.f, 0.f};

    // prologue: A[0] regs + B[0] glds; cvt A[0] -> buf0; A[1] regs in flight
    ALOAD(0)
    SB0G(0, 0) SB1G(0, 0)
    ACVT(0)                  // compiler-counted vmcnt(4) drains A[0]
    ALOAD(64)                // A[1]
    LGKM0                    // flush A ds_writes
    VM8                      // drain B[0]; A[1] (8) stays in flight
    BAR SCB

    bf16x8 af0[2][4], af1[2][4], bf0[2][2], bf1[2][2];

#define GTILE(CUR, NXT, T)                                                     \
    {                                                                          \
        const unsigned short* lA = lds + ((CUR) * 2 + wr) * 8192;              \
        const unsigned short* lB = lds + 32768 + ((CUR) * 2 + hb) * 8192;      \
        const bool pf = (T) + 1 < 16;                                          \
        const bool al = ((T) >= 1) && pf;                                      \
        const long k1 = (long)((T) + 1) * 64;                                  \
        /* ph0 */                                                              \
        RD_AF0(lA) RD_BF0(lB)                                                  \
        BAR LGKM0 SCB                                                          \
        P1 MG(af0, bf0, 0, 0) P0                                               \
        BAR                                                                    \
        /* ph1 */                                                              \
        RD_BF1(lB)                                                             \
        if (pf) { SB0G(NXT, k1) SB1G(NXT, k1) }                                \
        BAR LGKM0 SCB                                                          \
        P1 MG(af0, bf1, 0, 2) P0                                               \
        BAR                                                                    \
        /* ph2 */                                                              \
        RD_AF1(lA)                                                             \
        if (al) { ALOAD(k1 * 1) }                                              \
        BAR LGKM0 SCB                                                          \
        P1 MG(af1, bf0, 4, 0) P0                                               \
        BAR                                                                    \
        /* ph3 */                                                              \
        P1 MG(af1, bf1, 4, 2) P0                                               \
        if (pf) { ACVT(NXT) }                                                  \
        LGKM0                                                                  \
        if (pf) { VM0 }                                                        \
        BAR SCB                                                                \
    }

#pragma unroll
    for (int it = 0; it < 8; ++it) {
        GTILE(0, 1, 2 * it)
        GTILE(1, 0, 2 * it + 1)
    }
#undef GTILE
#undef ALOAD
#undef ACVT
#undef SB0G
#undef SB1G

    // ---- RMS scale: reduce per-row sumsq, lrow = rsqrt(mean) --------------
    spart[arow * 4 + acol] = sq0;
    spart[(128 + arow) * 4 + acol] = sq1;
    __syncthreads();
    if (tid < 256) {
        float s = spart[tid * 4] + spart[tid * 4 + 1] + spart[tid * 4 + 2] + spart[tid * 4 + 3];
        lrow[tid] = rsqrtf(s * (1.0f / 1024.0f));
    }
    __syncthreads();

    // ---- epilogue: apply l, pair gate/up lanes, SiLU, repack, store -------
#pragma unroll
    for (int ri = 0; ri < 8; ++ri)
#pragma unroll
        for (int rr = 0; rr < 4; ++rr) {
            int R = wr * 128 + ri * 16 + lhi * 4 + rr;
            float l = lrow[R];
#pragma unroll
            for (int cj = 0; cj < 4; ++cj) {
                float v = acc[ri][cj][rr] * l;
                float p = __shfl_xor(v, 1, 64);
                float g = (lane & 1) ? p : v;
                float u = (lane & 1) ? v : p;
                float s = (g / (1.0f + __expf(-g))) * u;
                if (!(lane & 1))
                    lds[R * 136 + wcq * 32 + cj * 8 + (llo >> 1)] = f2bf(s);
            }
        }
    __syncthreads();
    unsigned short* xg = x3 + (long)(mt * 256) * 512 + nt * 128;
#pragma unroll
    for (int i = 0; i < 8; ++i) {
        int c = i * 512 + tid;
        int row = c >> 4, ch = c & 15;
        *(bf16x8*)(xg + (long)row * 512 + ch * 8) = *(const bf16x8*)&lds[row * 136 + ch * 8];
    }
}

// ---------------------------------------------------------------------------
// Kernel 2: out = x3 @ w3t (M x 1024 fp32). 256x256 tile, K=512 -> 8 K-tiles.
// ---------------------------------------------------------------------------
__global__ __launch_bounds__(512, 2)
void down_gemm(const unsigned short* __restrict__ x3,
               const unsigned short* __restrict__ w3t,
               float* __restrict__ out) {
    __shared__ unsigned short lds[65536];
    const int tid = threadIdx.x;
    const int lane = tid & 63;
    const int wv = tid >> 6;
    const int wr = wv >> 2, wcq = wv & 3;
    const int lhi = lane >> 4, llo = lane & 15;

    int bid = blockIdx.x;
    int wgid = (bid & 7) * 256 + (bid >> 3);
    const int mt = wgid >> 2, nt = wgid & 3;

    f32x4 acc[8][4];
#pragma unroll
    for (int i = 0; i < 8; ++i)
#pragma unroll
        for (int j = 0; j < 4; ++j) acc[i][j] = (f32x4){0.f, 0.f, 0.f, 0.f};

    gemm256<8>(x3 + (long)mt * 256 * 512, w3t + (long)nt * 256 * 512,
               512, lds, acc, tid);

    float* op = out + (long)(mt * 256) * 1024 + nt * 256;
#pragma unroll
    for (int ri = 0; ri < 8; ++ri)
#pragma unroll
        for (int rr = 0; rr < 4; ++rr) {
            int R = wr * 128 + ri * 16 + lhi * 4 + rr;
#pragma unroll
            for (int cj = 0; cj < 4; ++cj)
                op[(long)R * 1024 + wcq * 64 + cj * 16 + llo] = acc[ri][cj][rr];
        }
}

// ---------------------------------------------------------------------------
extern "C" void kernel_launch(void* const* d_in, const int* in_sizes, int n_in,
                              void* d_out, int out_size, void* d_ws, size_t ws_size,
                              hipStream_t stream) {
    const float* x  = (const float*)d_in[0];
    const float* w0 = (const float*)d_in[1];
    const float* w1 = (const float*)d_in[2];
    const float* w2 = (const float*)d_in[3];
    const float* w3 = (const float*)d_in[4];
    float* out = (float*)d_out;

    unsigned short* w12t = (unsigned short*)d_ws;           // 2MB
    unsigned short* w3t  = w12t + 1024 * 1024;              // 1MB
    unsigned short* x3   = w3t + 1024 * 512;                // 128MB

    prep_w<<<dim3(6144), dim3(256), 0, stream>>>(w0, w1, w2, w3, w12t, w3t);
    gate_gemm<<<dim3(2048), dim3(512), 0, stream>>>(x, w12t, x3);
    down_gemm<<<dim3(2048), dim3(512), 0, stream>>>(x3, w3t, out);
}

// Round 11
// 709.814 us; speedup vs baseline: 1.2765x; 1.2765x over previous
//
#include <hip/hip_runtime.h>
#include <cstdint>

typedef __attribute__((ext_vector_type(4))) float f32x4;
typedef __attribute__((ext_vector_type(8))) short bf16x8;
typedef __attribute__((ext_vector_type(4))) short bf16x4;

#define DEV static __device__ __forceinline__

// round-to-nearest-even f32 -> bf16 (bit pattern)
DEV unsigned short f2bf(float f) {
    union { float f; unsigned int u; } v; v.f = f;
    unsigned int u = v.u;
    return (unsigned short)((u + 0x7FFFu + ((u >> 16) & 1u)) >> 16);
}

// async global->LDS 16B per lane; LDS dest = wave-uniform base + lane*16
DEV void async_cp16(const void* g, void* l) {
    __builtin_amdgcn_global_load_lds(
        (const __attribute__((address_space(1))) unsigned int*)g,
        (__attribute__((address_space(3))) unsigned int*)l,
        16, 0, 0);
}

#define BAR __builtin_amdgcn_s_barrier();
#define SCB __builtin_amdgcn_sched_barrier(0);
#define LGKM0 asm volatile("s_waitcnt lgkmcnt(0)");
#define P1 __builtin_amdgcn_s_setprio(1);
#define P0 __builtin_amdgcn_s_setprio(0);
#define VM0 asm volatile("s_waitcnt vmcnt(0)" ::: "memory");
#define VM2 asm volatile("s_waitcnt vmcnt(2)" ::: "memory");
#define VM3 asm volatile("s_waitcnt vmcnt(3)" ::: "memory");

// stage a 256x32 bf16 tile (16KB): 2 x 16B per thread; linear LDS dest,
// inverse-swizzled source (involution: slot ^= row&3 at 16B granules).
DEV void stage_A32(const unsigned short* __restrict__ g, long kofs,
                   unsigned short* l, int tid, int gp) {
#pragma unroll
    for (int i = 0; i < 2; ++i) {
        int c = i * 512 + tid;
        int row = c >> 2;
        int ss = (c & 3) ^ (row & 3);
        async_cp16(g + (long)row * gp + kofs + ss * 8,
                   l + (i * 512 + (tid & 448)) * 8);
    }
}
// stage a 128x32 bf16 tile (8KB): 1 x 16B per thread.
DEV void stage_B32(const unsigned short* __restrict__ g, long kofs,
                   unsigned short* l, int tid, int gp) {
    int row = tid >> 2;
    int ss = (tid & 3) ^ (row & 3);
    async_cp16(g + (long)row * gp + kofs + ss * 8, l + (tid & 448) * 8);
}

// ---------------------------------------------------------------------------
// 256x128 8-wave GEMM core, BK=32, 64KB LDS -> 2 blocks/CU (the overlap
// lever: one block's MFMA covers the other's LDS/barrier phases).
// LDS (ushorts): A bufs 0/8192/16384 (triple), B bufs 24576/28672 (double).
// Wave (wr=wv>>1 in 0..3, wc=wv&1) owns C rows [wr*64,+64) x cols [wc*64,+64).
// Per K-tile t: 2 phases {ds_read frags; stage; BAR; lgkm0; 8 MFMA; BAR}.
// Stage order: ph0(t) stages B(t+1) (t>=1), ph1(t) stages A(t+2).
// Gate at end ph1: vmcnt(2). Ledger (steady state): outstanding at gate =
// A(t+1)a,b , B(t+1) , A(t+2)a,b (oldest->newest) -> vmcnt(2) drains all of
// tile t+1, leaves A(t+2) in flight. Prologue: A0,B0,A1,B1 + vmcnt(3).
// Tail: t=NT-2 gates vmcnt(0); t=NT-1 no gate (loop-final BAR retained).
// Write-after-read: B(t+1)->pb1 whose last read (t-1) drained 2 barriers
// earlier; A(t+2)->pa2 whose last read was ph0(t-1). All wave-uniform bases.
// ---------------------------------------------------------------------------
template <int NT>
DEV void gemmB(const unsigned short* __restrict__ gA,
               const unsigned short* __restrict__ gB,
               const int gpa, const int gpb, unsigned short* lds,
               f32x4 (&acc)[4][4], const int tid) {
    const int lane = tid & 63;
    const int wv = tid >> 6;
    const int wr = wv >> 1, wc = wv & 1;
    const int lhi = lane >> 4, llo = lane & 15;
    // swizzled per-lane frag offsets (s = lhi ^ (llo&3) since row%4 == llo%4)
    const int sw = (lhi ^ (llo & 3)) << 3;
    const int aoff = (wr * 64 + llo) * 32 + sw;   // + i*512 per 16-row step
    const int boff = (wc * 64 + llo) * 32 + sw;   // + j*512

    unsigned short *pa0 = lds, *pa1 = lds + 8192, *pa2 = lds + 16384;
    unsigned short *pb0 = lds + 24576, *pb1 = lds + 28672;

#define MGJ(J)                                                                \
    _Pragma("unroll") for (int i = 0; i < 4; ++i)                             \
    _Pragma("unroll") for (int jj = 0; jj < 2; ++jj)                          \
        acc[i][(J) + jj] = __builtin_amdgcn_mfma_f32_16x16x32_bf16(           \
            af[i], bf[(J) + jj], acc[i][(J) + jj], 0, 0, 0);

    // prologue: A0,B0,A1,B1; drain A0,B0 (leave A1 pair + B1 in flight)
    stage_A32(gA, 0, pa0, tid, gpa);
    stage_B32(gB, 0, pb0, tid, gpb);
    stage_A32(gA, 32, pa1, tid, gpa);
    stage_B32(gB, 32, pb1, tid, gpb);
    VM3
    BAR SCB

    bf16x8 af[4], bf[4];
    for (int t = 0; t < NT; ++t) {
        const bool pf1 = (t + 1 < NT);
        const bool pf2 = (t + 2 < NT);
        // ---- ph0: read A frags + B j0,j1; stage B(t+1) -------------------
#pragma unroll
        for (int i = 0; i < 4; ++i) af[i] = *(const bf16x8*)&pa0[aoff + i * 512];
        bf[0] = *(const bf16x8*)&pb0[boff];
        bf[1] = *(const bf16x8*)&pb0[boff + 512];
        if (t >= 1 && pf1) stage_B32(gB, (long)(t + 1) * 32, pb1, tid, gpb);
        BAR LGKM0 SCB
        P1 MGJ(0) P0
        BAR
        // ---- ph1: read B j2,j3; stage A(t+2); gate -----------------------
        bf[2] = *(const bf16x8*)&pb0[boff + 1024];
        bf[3] = *(const bf16x8*)&pb0[boff + 1536];
        if (pf2) stage_A32(gA, (long)(t + 2) * 32, pa2, tid, gpa);
        BAR LGKM0 SCB
        P1 MGJ(2) P0
        if (pf1) { if (pf2) { VM2 } else { VM0 } }
        BAR SCB
        // rotate buffers
        unsigned short* tp = pa0; pa0 = pa1; pa1 = pa2; pa2 = tp;
        tp = pb0; pb0 = pb1; pb1 = tp;
    }
#undef MGJ
}

// ---------------------------------------------------------------------------
// Kernel 0: weight prep.
//  w12t[n][k]: n even -> bf16(w0[k]*w1[k][n/2]), n odd -> bf16(w0[k]*w2[k][n/2])
//  w3t[j][n] = bf16(w3[n][j])   (1024 x 512, n contiguous)
// ---------------------------------------------------------------------------
__global__ void prep_w(const float* __restrict__ w0, const float* __restrict__ w1,
                       const float* __restrict__ w2, const float* __restrict__ w3,
                       unsigned short* __restrict__ w12t, unsigned short* __restrict__ w3t) {
    int t = blockIdx.x * 256 + threadIdx.x;
    if (t < 1048576) {
        int n = t >> 10, k = t & 1023;
        const float* src = (n & 1) ? w2 : w1;
        w12t[t] = f2bf(w0[k] * src[k * 512 + (n >> 1)]);
    } else {
        int idx = t - 1048576;
        int j = idx >> 9, n = idx & 511;
        w3t[idx] = f2bf(w3[n * 1024 + j]);
    }
}

// ---------------------------------------------------------------------------
// Kernel 0b: RMSNorm fold. xb[row][k] = bf16(x[row][k] * rsqrt(mean(x^2)))
// ---------------------------------------------------------------------------
__global__ __launch_bounds__(256)
void prep_x(const float* __restrict__ x, unsigned short* __restrict__ xb) {
    const int wv = threadIdx.x >> 6, lane = threadIdx.x & 63;
    const int stride = gridDim.x * 4;
    for (int row = blockIdx.x * 4 + wv; row < 131072; row += stride) {
        const float* xr = x + (long)row * 1024;
        f32x4 v[4];
        float s = 0.f;
#pragma unroll
        for (int c = 0; c < 4; ++c) {
            v[c] = *(const f32x4*)(xr + c * 256 + lane * 4);
            s += v[c].x * v[c].x + v[c].y * v[c].y + v[c].z * v[c].z + v[c].w * v[c].w;
        }
#pragma unroll
        for (int off = 32; off > 0; off >>= 1) s += __shfl_xor(s, off, 64);
        float l = rsqrtf(s * (1.0f / 1024.0f));
        unsigned short* xo = xb + (long)row * 1024;
#pragma unroll
        for (int c = 0; c < 4; ++c) {
            bf16x4 b;
            b.x = (short)f2bf(v[c].x * l);
            b.y = (short)f2bf(v[c].y * l);
            b.z = (short)f2bf(v[c].z * l);
            b.w = (short)f2bf(v[c].w * l);
            *(bf16x4*)(xo + c * 256 + lane * 4) = b;
        }
    }
}

// ---------------------------------------------------------------------------
// Kernel 1: x3 = silu_gate(xb @ w12t^T). 256x128 tile (=64 out cols), K=1024
// -> NT=32. Grid 512x8 = 4096 blocks, 2 blocks/CU.
// ---------------------------------------------------------------------------
__global__ __launch_bounds__(512, 4)
void gate_gemm(const unsigned short* __restrict__ xb,
               const unsigned short* __restrict__ w12t,
               unsigned short* __restrict__ x3) {
    __shared__ unsigned short lds[32768];    // 64 KB
    const int tid = threadIdx.x;
    const int lane = tid & 63;
    const int wv = tid >> 6;
    const int wr = wv >> 1, wc = wv & 1;
    const int lhi = lane >> 4, llo = lane & 15;

    int bid = blockIdx.x;                    // 4096 blocks
    int wgid = (bid & 7) * 512 + (bid >> 3); // bijective XCD chunks
    const int mt = wgid >> 3, nt = wgid & 7;

    f32x4 acc[4][4];
#pragma unroll
    for (int i = 0; i < 4; ++i)
#pragma unroll
        for (int j = 0; j < 4; ++j) acc[i][j] = (f32x4){0.f, 0.f, 0.f, 0.f};

    gemmB<32>(xb + (long)mt * 256 * 1024, w12t + (long)nt * 128 * 1024,
              1024, 1024, lds, acc, tid);

    // ---- epilogue: pair even/odd interleaved cols (gate/up), SiLU, repack -
    // repack tile [256][72] ushorts (even lanes write; pitch 72 breaks banks)
#pragma unroll
    for (int i = 0; i < 4; ++i)
#pragma unroll
        for (int rr = 0; rr < 4; ++rr) {
            int R = wr * 64 + i * 16 + lhi * 4 + rr;
#pragma unroll
            for (int j = 0; j < 4; ++j) {
                float v = acc[i][j][rr];
                float p = __shfl_xor(v, 1, 64);
                float g = (lane & 1) ? p : v;
                float u = (lane & 1) ? v : p;
                float s = (g / (1.0f + __expf(-g))) * u;
                if (!(lane & 1))
                    lds[R * 72 + wc * 32 + j * 8 + (llo >> 1)] = f2bf(s);
            }
        }
    __syncthreads();
    // store: 256 rows x 64 ushorts = 2048 chunks of 16B, 4 per thread
    unsigned short* xg = x3 + (long)(mt * 256) * 512 + nt * 64;
#pragma unroll
    for (int i = 0; i < 4; ++i) {
        int c = i * 512 + tid;
        int row = c >> 3, ch = c & 7;
        *(bf16x8*)(xg + (long)row * 512 + ch * 8) = *(const bf16x8*)&lds[row * 72 + ch * 8];
    }
}

// ---------------------------------------------------------------------------
// Kernel 2: out = x3 @ w3t (M x 1024 fp32). 256x128 tile, K=512 -> NT=16.
// Grid 512x8 = 4096 blocks, 2 blocks/CU.
// ---------------------------------------------------------------------------
__global__ __launch_bounds__(512, 4)
void down_gemm(const unsigned short* __restrict__ x3,
               const unsigned short* __restrict__ w3t,
               float* __restrict__ out) {
    __shared__ unsigned short lds[32768];
    const int tid = threadIdx.x;
    const int lane = tid & 63;
    const int wv = tid >> 6;
    const int wr = wv >> 1, wc = wv & 1;
    const int lhi = lane >> 4, llo = lane & 15;

    int bid = blockIdx.x;                    // 4096 blocks
    int wgid = (bid & 7) * 512 + (bid >> 3);
    const int mt = wgid >> 3, nt = wgid & 7;

    f32x4 acc[4][4];
#pragma unroll
    for (int i = 0; i < 4; ++i)
#pragma unroll
        for (int j = 0; j < 4; ++j) acc[i][j] = (f32x4){0.f, 0.f, 0.f, 0.f};

    gemmB<16>(x3 + (long)mt * 256 * 512, w3t + (long)nt * 128 * 512,
              512, 512, lds, acc, tid);

    float* op = out + (long)(mt * 256) * 1024 + nt * 128;
#pragma unroll
    for (int i = 0; i < 4; ++i)
#pragma unroll
        for (int rr = 0; rr < 4; ++rr) {
            int R = wr * 64 + i * 16 + lhi * 4 + rr;
#pragma unroll
            for (int j = 0; j < 4; ++j)
                op[(long)R * 1024 + wc * 64 + j * 16 + llo] = acc[i][j][rr];
        }
}

// ---------------------------------------------------------------------------
extern "C" void kernel_launch(void* const* d_in, const int* in_sizes, int n_in,
                              void* d_out, int out_size, void* d_ws, size_t ws_size,
                              hipStream_t stream) {
    const float* x  = (const float*)d_in[0];
    const float* w0 = (const float*)d_in[1];
    const float* w1 = (const float*)d_in[2];
    const float* w2 = (const float*)d_in[3];
    const float* w3 = (const float*)d_in[4];
    float* out = (float*)d_out;

    unsigned short* w12t = (unsigned short*)d_ws;           // 2MB
    unsigned short* w3t  = w12t + 1024 * 1024;              // 1MB
    unsigned short* x3   = w3t + 1024 * 512;                // 128MB
    unsigned short* xb   = x3 + (size_t)131072 * 512;       // 256MB

    prep_w<<<dim3(6144), dim3(256), 0, stream>>>(w0, w1, w2, w3, w12t, w3t);
    prep_x<<<dim3(2048), dim3(256), 0, stream>>>(x, xb);
    gate_gemm<<<dim3(4096), dim3(512), 0, stream>>>(xb, w12t, x3);
    down_gemm<<<dim3(4096), dim3(512), 0, stream>>>(x3, w3t, out);
}

// Round 12
// 697.774 us; speedup vs baseline: 1.2986x; 1.0173x over previous
//
#include <hip/hip_runtime.h>
#include <cstdint>

typedef __attribute__((ext_vector_type(4))) float f32x4;
typedef __attribute__((ext_vector_type(8))) short bf16x8;
typedef __attribute__((ext_vector_type(4))) short bf16x4;

#define DEV static __device__ __forceinline__

// round-to-nearest-even f32 -> bf16 (bit pattern)
DEV unsigned short f2bf(float f) {
    union { float f; unsigned int u; } v; v.f = f;
    unsigned int u = v.u;
    return (unsigned short)((u + 0x7FFFu + ((u >> 16) & 1u)) >> 16);
}

// async global->LDS 16B per lane; LDS dest = wave-uniform base + lane*16
DEV void async_cp16(const void* g, void* l) {
    __builtin_amdgcn_global_load_lds(
        (const __attribute__((address_space(1))) unsigned int*)g,
        (__attribute__((address_space(3))) unsigned int*)l,
        16, 0, 0);
}

#define BAR __builtin_amdgcn_s_barrier();
#define SCB __builtin_amdgcn_sched_barrier(0);
#define LGKM0 asm volatile("s_waitcnt lgkmcnt(0)");
#define P1 __builtin_amdgcn_s_setprio(1);
#define P0 __builtin_amdgcn_s_setprio(0);
#define VM0 asm volatile("s_waitcnt vmcnt(0)" ::: "memory");
#define VM2 asm volatile("s_waitcnt vmcnt(2)" ::: "memory");
#define VM3 asm volatile("s_waitcnt vmcnt(3)" ::: "memory");

// stage a 256x32 bf16 tile (16KB): 2 x 16B per thread; linear LDS dest,
// inverse-swizzled source. Involution for 64B row pitch: slot ^= (row>>1)&3
// (bank-group G = 4*(row&1) + slot^((row>>1)&3) covers all 8 groups per 8
// rows -> 2-way over 16 lanes = free).
DEV void stage_A32(const unsigned short* __restrict__ g, long kofs,
                   unsigned short* l, int tid, int gp) {
#pragma unroll
    for (int i = 0; i < 2; ++i) {
        int c = i * 512 + tid;
        int row = c >> 2;
        int ss = (c & 3) ^ ((row >> 1) & 3);
        async_cp16(g + (long)row * gp + kofs + ss * 8,
                   l + (i * 512 + (tid & 448)) * 8);
    }
}
// stage a 128x32 bf16 tile (8KB): 1 x 16B per thread.
DEV void stage_B32(const unsigned short* __restrict__ g, long kofs,
                   unsigned short* l, int tid, int gp) {
    int row = tid >> 2;
    int ss = (tid & 3) ^ ((row >> 1) & 3);
    async_cp16(g + (long)row * gp + kofs + ss * 8, l + (tid & 448) * 8);
}

// ---------------------------------------------------------------------------
// 256x128 8-wave GEMM core, BK=32, 64KB LDS -> 2 blocks/CU (the overlap
// lever: one block's MFMA covers the other's LDS/barrier phases).
// LDS (ushorts): A bufs 0/8192/16384 (triple), B bufs 24576/28672 (double).
// Wave (wr=wv>>1 in 0..3, wc=wv&1) owns C rows [wr*64,+64) x cols [wc*64,+64).
// Per K-tile t: 2 phases {ds_read frags; stage; BAR; lgkm0; 8 MFMA; BAR}.
// Stage order: ph0(t) stages B(t+1) (t>=1), ph1(t) stages A(t+2).
// Gate at end ph1: vmcnt(2). Ledger (steady state): outstanding at gate =
// A(t+1)a,b , B(t+1) , A(t+2)a,b (oldest->newest) -> vmcnt(2) drains all of
// tile t+1, leaves A(t+2) in flight. Prologue: A0,B0,A1,B1 + vmcnt(3).
// Tail: t=NT-2 gates vmcnt(0); t=NT-1 no gate (loop-final BAR retained).
// Write-after-read: B(t+1)->pb1 whose last read (t-1) drained 2 barriers
// earlier; A(t+2)->pa2 whose last read was ph0(t-1). All wave-uniform bases.
// ---------------------------------------------------------------------------
template <int NT>
DEV void gemmB(const unsigned short* __restrict__ gA,
               const unsigned short* __restrict__ gB,
               const int gpa, const int gpb, unsigned short* lds,
               f32x4 (&acc)[4][4], const int tid) {
    const int lane = tid & 63;
    const int wv = tid >> 6;
    const int wr = wv >> 1, wc = wv & 1;
    const int lhi = lane >> 4, llo = lane & 15;
    // swizzled per-lane frag offsets; frag row = base + llo with base%4==0,
    // so (row>>1)&3 == (llo>>1)&3 for all frags (i*16, wr*64 are mult. of 4)
    const int sw = (lhi ^ ((llo >> 1) & 3)) << 3;
    const int aoff = (wr * 64 + llo) * 32 + sw;   // + i*512 per 16-row step
    const int boff = (wc * 64 + llo) * 32 + sw;   // + j*512

    unsigned short *pa0 = lds, *pa1 = lds + 8192, *pa2 = lds + 16384;
    unsigned short *pb0 = lds + 24576, *pb1 = lds + 28672;

#define MGJ(J)                                                                \
    _Pragma("unroll") for (int i = 0; i < 4; ++i)                             \
    _Pragma("unroll") for (int jj = 0; jj < 2; ++jj)                          \
        acc[i][(J) + jj] = __builtin_amdgcn_mfma_f32_16x16x32_bf16(           \
            af[i], bf[(J) + jj], acc[i][(J) + jj], 0, 0, 0);

    // prologue: A0,B0,A1,B1; drain A0,B0 (leave A1 pair + B1 in flight)
    stage_A32(gA, 0, pa0, tid, gpa);
    stage_B32(gB, 0, pb0, tid, gpb);
    stage_A32(gA, 32, pa1, tid, gpa);
    stage_B32(gB, 32, pb1, tid, gpb);
    VM3
    BAR SCB

    bf16x8 af[4], bf[4];
    for (int t = 0; t < NT; ++t) {
        const bool pf1 = (t + 1 < NT);
        const bool pf2 = (t + 2 < NT);
        // ---- ph0: read A frags + B j0,j1; stage B(t+1) -------------------
#pragma unroll
        for (int i = 0; i < 4; ++i) af[i] = *(const bf16x8*)&pa0[aoff + i * 512];
        bf[0] = *(const bf16x8*)&pb0[boff];
        bf[1] = *(const bf16x8*)&pb0[boff + 512];
        if (t >= 1 && pf1) stage_B32(gB, (long)(t + 1) * 32, pb1, tid, gpb);
        BAR LGKM0 SCB
        P1 MGJ(0) P0
        BAR
        // ---- ph1: read B j2,j3; stage A(t+2); gate -----------------------
        bf[2] = *(const bf16x8*)&pb0[boff + 1024];
        bf[3] = *(const bf16x8*)&pb0[boff + 1536];
        if (pf2) stage_A32(gA, (long)(t + 2) * 32, pa2, tid, gpa);
        BAR LGKM0 SCB
        P1 MGJ(2) P0
        if (pf1) { if (pf2) { VM2 } else { VM0 } }
        BAR SCB
        // rotate buffers
        unsigned short* tp = pa0; pa0 = pa1; pa1 = pa2; pa2 = tp;
        tp = pb0; pb0 = pb1; pb1 = tp;
    }
#undef MGJ
}

// ---------------------------------------------------------------------------
// Kernel 0: weight prep.
//  w12t[n][k]: n even -> bf16(w0[k]*w1[k][n/2]), n odd -> bf16(w0[k]*w2[k][n/2])
//  w3t[j][n] = bf16(w3[n][j])   (1024 x 512, n contiguous)
// ---------------------------------------------------------------------------
__global__ void prep_w(const float* __restrict__ w0, const float* __restrict__ w1,
                       const float* __restrict__ w2, const float* __restrict__ w3,
                       unsigned short* __restrict__ w12t, unsigned short* __restrict__ w3t) {
    int t = blockIdx.x * 256 + threadIdx.x;
    if (t < 1048576) {
        int n = t >> 10, k = t & 1023;
        const float* src = (n & 1) ? w2 : w1;
        w12t[t] = f2bf(w0[k] * src[k * 512 + (n >> 1)]);
    } else {
        int idx = t - 1048576;
        int j = idx >> 9, n = idx & 511;
        w3t[idx] = f2bf(w3[n * 1024 + j]);
    }
}

// ---------------------------------------------------------------------------
// Kernel 0b: RMSNorm fold. xb[row][k] = bf16(x[row][k] * rsqrt(mean(x^2)))
// ---------------------------------------------------------------------------
__global__ __launch_bounds__(256)
void prep_x(const float* __restrict__ x, unsigned short* __restrict__ xb) {
    const int wv = threadIdx.x >> 6, lane = threadIdx.x & 63;
    const int stride = gridDim.x * 4;
    for (int row = blockIdx.x * 4 + wv; row < 131072; row += stride) {
        const float* xr = x + (long)row * 1024;
        f32x4 v[4];
        float s = 0.f;
#pragma unroll
        for (int c = 0; c < 4; ++c) {
            v[c] = *(const f32x4*)(xr + c * 256 + lane * 4);
            s += v[c].x * v[c].x + v[c].y * v[c].y + v[c].z * v[c].z + v[c].w * v[c].w;
        }
#pragma unroll
        for (int off = 32; off > 0; off >>= 1) s += __shfl_xor(s, off, 64);
        float l = rsqrtf(s * (1.0f / 1024.0f));
        unsigned short* xo = xb + (long)row * 1024;
#pragma unroll
        for (int c = 0; c < 4; ++c) {
            bf16x4 b;
            b.x = (short)f2bf(v[c].x * l);
            b.y = (short)f2bf(v[c].y * l);
            b.z = (short)f2bf(v[c].z * l);
            b.w = (short)f2bf(v[c].w * l);
            *(bf16x4*)(xo + c * 256 + lane * 4) = b;
        }
    }
}

// ---------------------------------------------------------------------------
// Kernel 1: x3 = silu_gate(xb @ w12t^T). 256x128 tile (=64 out cols), K=1024
// -> NT=32. Grid 512x8 = 4096 blocks, 2 blocks/CU.
// ---------------------------------------------------------------------------
__global__ __launch_bounds__(512, 4)
void gate_gemm(const unsigned short* __restrict__ xb,
               const unsigned short* __restrict__ w12t,
               unsigned short* __restrict__ x3) {
    __shared__ unsigned short lds[32768];    // 64 KB
    const int tid = threadIdx.x;
    const int lane = tid & 63;
    const int wv = tid >> 6;
    const int wr = wv >> 1, wc = wv & 1;
    const int lhi = lane >> 4, llo = lane & 15;

    int bid = blockIdx.x;                    // 4096 blocks
    int wgid = (bid & 7) * 512 + (bid >> 3); // bijective XCD chunks
    const int mt = wgid >> 3, nt = wgid & 7;

    f32x4 acc[4][4];
#pragma unroll
    for (int i = 0; i < 4; ++i)
#pragma unroll
        for (int j = 0; j < 4; ++j) acc[i][j] = (f32x4){0.f, 0.f, 0.f, 0.f};

    gemmB<32>(xb + (long)mt * 256 * 1024, w12t + (long)nt * 128 * 1024,
              1024, 1024, lds, acc, tid);

    // ---- epilogue: pair even/odd interleaved cols (gate/up), SiLU, repack -
    // repack tile [256][72] ushorts (even lanes write; pitch 72 breaks banks)
#pragma unroll
    for (int i = 0; i < 4; ++i)
#pragma unroll
        for (int rr = 0; rr < 4; ++rr) {
            int R = wr * 64 + i * 16 + lhi * 4 + rr;
#pragma unroll
            for (int j = 0; j < 4; ++j) {
                float v = acc[i][j][rr];
                float p = __shfl_xor(v, 1, 64);
                float g = (lane & 1) ? p : v;
                float u = (lane & 1) ? v : p;
                float s = (g / (1.0f + __expf(-g))) * u;
                if (!(lane & 1))
                    lds[R * 72 + wc * 32 + j * 8 + (llo >> 1)] = f2bf(s);
            }
        }
    __syncthreads();
    // store: 256 rows x 64 ushorts = 2048 chunks of 16B, 4 per thread
    unsigned short* xg = x3 + (long)(mt * 256) * 512 + nt * 64;
#pragma unroll
    for (int i = 0; i < 4; ++i) {
        int c = i * 512 + tid;
        int row = c >> 3, ch = c & 7;
        *(bf16x8*)(xg + (long)row * 512 + ch * 8) = *(const bf16x8*)&lds[row * 72 + ch * 8];
    }
}

// ---------------------------------------------------------------------------
// Kernel 2: out = x3 @ w3t (M x 1024 fp32). 256x128 tile, K=512 -> NT=16.
// Grid 512x8 = 4096 blocks, 2 blocks/CU.
// ---------------------------------------------------------------------------
__global__ __launch_bounds__(512, 4)
void down_gemm(const unsigned short* __restrict__ x3,
               const unsigned short* __restrict__ w3t,
               float* __restrict__ out) {
    __shared__ unsigned short lds[32768];
    const int tid = threadIdx.x;
    const int lane = tid & 63;
    const int wv = tid >> 6;
    const int wr = wv >> 1, wc = wv & 1;
    const int lhi = lane >> 4, llo = lane & 15;

    int bid = blockIdx.x;                    // 4096 blocks
    int wgid = (bid & 7) * 512 + (bid >> 3);
    const int mt = wgid >> 3, nt = wgid & 7;

    f32x4 acc[4][4];
#pragma unroll
    for (int i = 0; i < 4; ++i)
#pragma unroll
        for (int j = 0; j < 4; ++j) acc[i][j] = (f32x4){0.f, 0.f, 0.f, 0.f};

    gemmB<16>(x3 + (long)mt * 256 * 512, w3t + (long)nt * 128 * 512,
              512, 512, lds, acc, tid);

    float* op = out + (long)(mt * 256) * 1024 + nt * 128;
#pragma unroll
    for (int i = 0; i < 4; ++i)
#pragma unroll
        for (int rr = 0; rr < 4; ++rr) {
            int R = wr * 64 + i * 16 + lhi * 4 + rr;
#pragma unroll
            for (int j = 0; j < 4; ++j)
                op[(long)R * 1024 + wc * 64 + j * 16 + llo] = acc[i][j][rr];
        }
}

// ---------------------------------------------------------------------------
extern "C" void kernel_launch(void* const* d_in, const int* in_sizes, int n_in,
                              void* d_out, int out_size, void* d_ws, size_t ws_size,
                              hipStream_t stream) {
    const float* x  = (const float*)d_in[0];
    const float* w0 = (const float*)d_in[1];
    const float* w1 = (const float*)d_in[2];
    const float* w2 = (const float*)d_in[3];
    const float* w3 = (const float*)d_in[4];
    float* out = (float*)d_out;

    unsigned short* w12t = (unsigned short*)d_ws;           // 2MB
    unsigned short* w3t  = w12t + 1024 * 1024;              // 1MB
    unsigned short* x3   = w3t + 1024 * 512;                // 128MB
    unsigned short* xb   = x3 + (size_t)131072 * 512;       // 256MB

    prep_w<<<dim3(6144), dim3(256), 0, stream>>>(w0, w1, w2, w3, w12t, w3t);
    prep_x<<<dim3(2048), dim3(256), 0, stream>>>(x, xb);
    gate_gemm<<<dim3(4096), dim3(512), 0, stream>>>(xb, w12t, x3);
    down_gemm<<<dim3(4096), dim3(512), 0, stream>>>(x3, w3t, out);
}